// Round 1
// baseline (269.455 us; speedup 1.0000x reference)
//
#include <hip/hip_runtime.h>
#include <hip/hip_bf16.h>
#include <stdint.h>

typedef unsigned short u16;
typedef short bf16x8 __attribute__((ext_vector_type(8)));
typedef float f32x4 __attribute__((ext_vector_type(4)));

#define DEVI static __device__ __forceinline__

#if __has_builtin(__builtin_amdgcn_exp2f)
#define EXP2F(x) __builtin_amdgcn_exp2f(x)
#else
#define EXP2F(x) exp2f(x)
#endif

DEVI u16 f2bf(float f) {
  union { float f; uint32_t u; } v; v.f = f;
  uint32_t u = v.u;
  u += 0x7fffu + ((u >> 16) & 1u);   // round-to-nearest-even
  return (u16)(u >> 16);
}

DEVI void async16(const void* g, const void* l) {
  __builtin_amdgcn_global_load_lds(
      (const __attribute__((address_space(1))) void*)g,
      (__attribute__((address_space(3))) void*)l, 16, 0, 0);
}

DEVI f32x4 mfma16(bf16x8 a, bf16x8 b, f32x4 c) {
  return __builtin_amdgcn_mfma_f32_16x16x32_bf16(a, b, c, 0, 0, 0);
}

DEVI float rmax16(float v) {
  v = fmaxf(v, __shfl_xor(v, 1, 16));
  v = fmaxf(v, __shfl_xor(v, 2, 16));
  v = fmaxf(v, __shfl_xor(v, 4, 16));
  v = fmaxf(v, __shfl_xor(v, 8, 16));
  return v;
}
DEVI float rsum16(float v) {
  v += __shfl_xor(v, 1, 16);
  v += __shfl_xor(v, 2, 16);
  v += __shfl_xor(v, 4, 16);
  v += __shfl_xor(v, 8, 16);
  return v;
}

// ---------------------------------------------------------------- constants
// B=2, S=2048, H=1024, NH=16, D=64, M=B*S=4096

// ------------------------------------------------- kernel 1: fp32 -> bf16 x
__global__ void convx(const float* __restrict__ q, const float* __restrict__ k,
                      const float* __restrict__ v, u16* __restrict__ out) {
  const int z = blockIdx.y;
  const float* src = (z == 0) ? q : (z == 1) ? k : v;
  const int i = (blockIdx.x * 256 + threadIdx.x) * 4;
  float4 f = *(const float4*)(src + i);
  ushort4 o;
  o.x = f2bf(f.x); o.y = f2bf(f.y); o.z = f2bf(f.z); o.w = f2bf(f.w);
  *(ushort4*)(out + (size_t)z * 4194304 + i) = o;
}

// ----------------------------------- kernel 2: W[k][n] -> Wt[n][k] in bf16
__global__ void transw(const float* __restrict__ Wq, const float* __restrict__ Wk,
                       const float* __restrict__ Wv, const float* __restrict__ Wo,
                       u16* __restrict__ WT) {
  __shared__ u16 tile[64 * 68];
  const int z = blockIdx.z;
  const float* W = (z == 0) ? Wq : (z == 1) ? Wk : (z == 2) ? Wv : Wo;
  u16* out = WT + (size_t)z * 1048576;
  const int R0 = blockIdx.y * 64, C0 = blockIdx.x * 64;
  const int t = threadIdx.x;
#pragma unroll
  for (int it = 0; it < 16; ++it) {
    int j = it * 256 + t;
    int r = j >> 6, c = j & 63;
    tile[r * 68 + c] = f2bf(W[(size_t)(R0 + r) * 1024 + C0 + c]);
  }
  __syncthreads();
#pragma unroll
  for (int it = 0; it < 16; ++it) {
    int j = it * 256 + t;
    int c = j >> 6, r = j & 63;
    out[(size_t)(C0 + c) * 1024 + R0 + r] = tile[r * 68 + c];
  }
}

// -------------------------------------------------- fused QKV projection GEMM
// C[m][n] = X[m][k] * W[k][n] + b[n].  A row-major [4096][1024] bf16,
// Bt N-major [1024][1024] bf16.  z=0:Q z=1:K -> [b,h,s,d]; z=2:V -> [b,h,d,s]
__global__ __launch_bounds__(256, 3)
void qkv_gemm(const u16* __restrict__ XB, const u16* __restrict__ WT,
              const float* __restrict__ bq, const float* __restrict__ bk,
              const float* __restrict__ bv,
              u16* __restrict__ QH, u16* __restrict__ KH, u16* __restrict__ VT) {
  __shared__ u16 lA[128 * 32];
  __shared__ u16 lB[128 * 32];
  const int z = blockIdx.z;
  const u16* A  = XB + (size_t)z * 4194304;
  const u16* Bt = WT + (size_t)z * 1048576;
  const float* bias = (z == 0) ? bq : (z == 1) ? bk : bv;
  const int t = threadIdx.x, lane = t & 63, w = t >> 6;
  const int quad = lane >> 4, l16 = lane & 15;
  const int wm = (w & 1) * 64, wn = (w >> 1) * 64;
  const int n0 = blockIdx.x * 128, m0 = blockIdx.y * 128;

  f32x4 acc[4][4] = {};
  for (int kt = 0; kt < 32; ++kt) {
    const int k0 = kt * 32;
#pragma unroll
    for (int it = 0; it < 2; ++it) {
      int i = it * 256 + w * 64 + lane;
      int r = i >> 2, cc = i & 3, c = cc ^ (r & 3);
      async16(A + (size_t)(m0 + r) * 1024 + k0 + c * 8, &lA[(it * 256 + w * 64) * 8]);
      async16(Bt + (size_t)(n0 + r) * 1024 + k0 + c * 8, &lB[(it * 256 + w * 64) * 8]);
    }
    __syncthreads();
    bf16x8 af[4], bfr[4];
#pragma unroll
    for (int rt = 0; rt < 4; ++rt) {
      int row = wm + rt * 16 + l16;
      af[rt] = *(const bf16x8*)&lA[row * 32 + (quad ^ (row & 3)) * 8];
    }
#pragma unroll
    for (int ct = 0; ct < 4; ++ct) {
      int row = wn + ct * 16 + l16;
      bfr[ct] = *(const bf16x8*)&lB[row * 32 + (quad ^ (row & 3)) * 8];
    }
#pragma unroll
    for (int rt = 0; rt < 4; ++rt)
#pragma unroll
      for (int ct = 0; ct < 4; ++ct)
        acc[rt][ct] = mfma16(af[rt], bfr[ct], acc[rt][ct]);
    __syncthreads();
  }

  float bvv[4];
  int ncol[4];
#pragma unroll
  for (int ct = 0; ct < 4; ++ct) {
    ncol[ct] = n0 + wn + ct * 16 + l16;
    bvv[ct] = bias[ncol[ct]];
  }
  if (z < 2) {
    u16* out = (z == 0) ? QH : KH;
#pragma unroll
    for (int rt = 0; rt < 4; ++rt)
#pragma unroll
      for (int r = 0; r < 4; ++r) {
        int m = m0 + wm + rt * 16 + quad * 4 + r;
        int bb = m >> 11, s = m & 2047;
#pragma unroll
        for (int ct = 0; ct < 4; ++ct) {
          int hh = ncol[ct] >> 6, d = ncol[ct] & 63;
          out[((size_t)((bb * 16 + hh) * 2048 + s)) * 64 + d] =
              f2bf(acc[rt][ct][r] + bvv[ct]);
        }
      }
  } else {
#pragma unroll
    for (int rt = 0; rt < 4; ++rt) {
      int mb = m0 + wm + rt * 16 + quad * 4;
      int bb = mb >> 11, sb = mb & 2047;
#pragma unroll
      for (int ct = 0; ct < 4; ++ct) {
        int hh = ncol[ct] >> 6, d = ncol[ct] & 63;
        ushort4 pk;
        pk.x = f2bf(acc[rt][ct][0] + bvv[ct]);
        pk.y = f2bf(acc[rt][ct][1] + bvv[ct]);
        pk.z = f2bf(acc[rt][ct][2] + bvv[ct]);
        pk.w = f2bf(acc[rt][ct][3] + bvv[ct]);
        *(ushort4*)&VT[((size_t)((bb * 16 + hh) * 64 + d)) * 2048 + sb] = pk;
      }
    }
  }
}

// -------------------------------------------------------- flash attention
// grid (qt=16, h=16, b=2); block 256 (4 waves); each block: 128 q rows.
__global__ __launch_bounds__(256, 2)
void attn_kernel(const u16* __restrict__ QH, const u16* __restrict__ KH,
                 const u16* __restrict__ VT, u16* __restrict__ AO) {
  __shared__ u16 lQ[128 * 64];
  __shared__ u16 lK[128 * 64];
  __shared__ u16 lV[64 * 128];
  __shared__ u16 lP[4][32 * 128];
  const int qt = blockIdx.x, h = blockIdx.y, b = blockIdx.z;
  const int t = threadIdx.x, lane = t & 63, w = t >> 6;
  const int quad = lane >> 4, l16 = lane & 15;
  const u16* Qg = QH + ((size_t)((b * 16 + h) * 2048 + qt * 128)) * 64;
  const u16* Kg = KH + ((size_t)((b * 16 + h) * 2048)) * 64;
  const u16* Vg = VT + ((size_t)((b * 16 + h) * 64)) * 2048;

  // stage Q tile [128][64], chunk-swizzled
#pragma unroll
  for (int it = 0; it < 4; ++it) {
    int i = w * 256 + it * 64 + lane;
    int r = i >> 3, cc = i & 7, c = cc ^ (r & 7);
    async16(Qg + (size_t)r * 64 + c * 8, &lQ[(w * 256 + it * 64) * 8]);
  }
  __syncthreads();
  bf16x8 qf[2][2];
#pragma unroll
  for (int rt = 0; rt < 2; ++rt)
#pragma unroll
    for (int ks = 0; ks < 2; ++ks) {
      int row = w * 32 + rt * 16 + l16;
      int cc = (ks * 4 + quad) ^ (row & 7);
      qf[rt][ks] = *(const bf16x8*)&lQ[row * 64 + cc * 8];
    }

  f32x4 o[2][4] = {};
  float mrun[2][4], lrun[2][4];
#pragma unroll
  for (int rt = 0; rt < 2; ++rt)
#pragma unroll
    for (int r = 0; r < 4; ++r) { mrun[rt][r] = -1e30f; lrun[rt][r] = 0.0f; }

  const float csc = 0.18033688011112042f;  // log2(e)/sqrt(64)

  for (int kt = 0; kt < 16; ++kt) {
    __syncthreads();  // protect lK/lV from previous iteration's readers
#pragma unroll
    for (int it = 0; it < 4; ++it) {
      int i = w * 256 + it * 64 + lane;
      int r = i >> 3, cc = i & 7, c = cc ^ (r & 7);
      async16(Kg + (size_t)kt * 8192 + (size_t)r * 64 + c * 8,
              &lK[(w * 256 + it * 64) * 8]);
    }
#pragma unroll
    for (int it = 0; it < 4; ++it) {
      int i = w * 256 + it * 64 + lane;
      int r = i >> 4, cc = i & 15, c = cc ^ (r & 7);
      async16(Vg + (size_t)r * 2048 + kt * 128 + c * 8,
              &lV[(w * 256 + it * 64) * 8]);
    }
    __syncthreads();

    // ---- QK^T: scores tile 32(q rows of this wave) x 128(sk)
    f32x4 sc[2][8] = {};
#pragma unroll
    for (int ks = 0; ks < 2; ++ks)
#pragma unroll
      for (int ct = 0; ct < 8; ++ct) {
        int row = ct * 16 + l16;
        int cc = (ks * 4 + quad) ^ (row & 7);
        bf16x8 kf = *(const bf16x8*)&lK[row * 64 + cc * 8];
        sc[0][ct] = mfma16(qf[0][ks], kf, sc[0][ct]);
        sc[1][ct] = mfma16(qf[1][ks], kf, sc[1][ct]);
      }

    // ---- online softmax (exp2 domain), write P to per-wave LDS
#pragma unroll
    for (int rt = 0; rt < 2; ++rt)
#pragma unroll
      for (int r = 0; r < 4; ++r) {
        float vm = sc[rt][0][r];
#pragma unroll
        for (int ct = 1; ct < 8; ++ct) vm = fmaxf(vm, sc[rt][ct][r]);
        vm = rmax16(vm) * csc;
        float mo = mrun[rt][r];
        float mn = fmaxf(mo, vm);
        float alpha = EXP2F(mo - mn);
        mrun[rt][r] = mn;
        float rs = 0.0f;
        int prow = rt * 16 + quad * 4 + r;
#pragma unroll
        for (int ct = 0; ct < 8; ++ct) {
          float p = EXP2F(sc[rt][ct][r] * csc - mn);
          rs += p;
          int col = ct * 16 + l16;
          lP[w][prow * 128 + (((col >> 3) ^ (prow & 7)) * 8) + (col & 7)] = f2bf(p);
        }
        rs = rsum16(rs);
        lrun[rt][r] = lrun[rt][r] * alpha + rs;
#pragma unroll
        for (int dt = 0; dt < 4; ++dt) o[rt][dt][r] *= alpha;
      }

    // ---- PV: O += P(32x128) * V(128x64)
#pragma unroll
    for (int ks2 = 0; ks2 < 4; ++ks2) {
      bf16x8 pf[2];
#pragma unroll
      for (int rt = 0; rt < 2; ++rt) {
        int prow = rt * 16 + l16;
        int cc = (ks2 * 4 + quad) ^ (prow & 7);
        pf[rt] = *(const bf16x8*)&lP[w][prow * 128 + cc * 8];
      }
#pragma unroll
      for (int dt = 0; dt < 4; ++dt) {
        int vrow = dt * 16 + l16;
        int cc = (ks2 * 4 + quad) ^ (vrow & 7);
        bf16x8 vf = *(const bf16x8*)&lV[vrow * 128 + cc * 8];
        o[0][dt] = mfma16(pf[0], vf, o[0][dt]);
        o[1][dt] = mfma16(pf[1], vf, o[1][dt]);
      }
    }
  }

  // ---- epilogue: O / l  -> AO [b][s][h*64+d] bf16
#pragma unroll
  for (int rt = 0; rt < 2; ++rt)
#pragma unroll
    for (int r = 0; r < 4; ++r) {
      float inv = 1.0f / lrun[rt][r];
      int q = qt * 128 + w * 32 + rt * 16 + quad * 4 + r;
      size_t base = ((size_t)(b * 2048 + q)) * 1024 + h * 64;
#pragma unroll
      for (int dt = 0; dt < 4; ++dt)
        AO[base + dt * 16 + l16] = f2bf(o[rt][dt][r] * inv);
    }
}

// ------------------------------------------------------- output projection
__global__ __launch_bounds__(256, 3)
void oproj_gemm(const u16* __restrict__ AO, const u16* __restrict__ Bt,
                const float* __restrict__ bias, float* __restrict__ out) {
  __shared__ u16 lA[128 * 32];
  __shared__ u16 lB[128 * 32];
  const int t = threadIdx.x, lane = t & 63, w = t >> 6;
  const int quad = lane >> 4, l16 = lane & 15;
  const int wm = (w & 1) * 64, wn = (w >> 1) * 64;
  const int n0 = blockIdx.x * 128, m0 = blockIdx.y * 128;

  f32x4 acc[4][4] = {};
  for (int kt = 0; kt < 32; ++kt) {
    const int k0 = kt * 32;
#pragma unroll
    for (int it = 0; it < 2; ++it) {
      int i = it * 256 + w * 64 + lane;
      int r = i >> 2, cc = i & 3, c = cc ^ (r & 3);
      async16(AO + (size_t)(m0 + r) * 1024 + k0 + c * 8, &lA[(it * 256 + w * 64) * 8]);
      async16(Bt + (size_t)(n0 + r) * 1024 + k0 + c * 8, &lB[(it * 256 + w * 64) * 8]);
    }
    __syncthreads();
    bf16x8 af[4], bfr[4];
#pragma unroll
    for (int rt = 0; rt < 4; ++rt) {
      int row = wm + rt * 16 + l16;
      af[rt] = *(const bf16x8*)&lA[row * 32 + (quad ^ (row & 3)) * 8];
    }
#pragma unroll
    for (int ct = 0; ct < 4; ++ct) {
      int row = wn + ct * 16 + l16;
      bfr[ct] = *(const bf16x8*)&lB[row * 32 + (quad ^ (row & 3)) * 8];
    }
#pragma unroll
    for (int rt = 0; rt < 4; ++rt)
#pragma unroll
      for (int ct = 0; ct < 4; ++ct)
        acc[rt][ct] = mfma16(af[rt], bfr[ct], acc[rt][ct]);
    __syncthreads();
  }

#pragma unroll
  for (int ct = 0; ct < 4; ++ct) {
    int ncol = n0 + wn + ct * 16 + l16;
    float bvv = bias[ncol];
#pragma unroll
    for (int rt = 0; rt < 4; ++rt)
#pragma unroll
      for (int r = 0; r < 4; ++r) {
        int m = m0 + wm + rt * 16 + quad * 4 + r;
        out[(size_t)m * 1024 + ncol] = acc[rt][ct][r] + bvv;
      }
  }
}

// ------------------------------------------------------------------ launch
extern "C" void kernel_launch(void* const* d_in, const int* in_sizes, int n_in,
                              void* d_out, int out_size, void* d_ws, size_t ws_size,
                              hipStream_t stream) {
  const float* query = (const float*)d_in[0];
  const float* key   = (const float*)d_in[1];
  const float* value = (const float*)d_in[2];
  const float* Wq = (const float*)d_in[3];
  const float* bq = (const float*)d_in[4];
  const float* Wk = (const float*)d_in[5];
  const float* bk = (const float*)d_in[6];
  const float* Wv = (const float*)d_in[7];
  const float* bv = (const float*)d_in[8];
  const float* Wo = (const float*)d_in[9];
  const float* bo = (const float*)d_in[10];
  float* out = (float*)d_out;

  // workspace layout (u16 elements): total 28M u16 = 56 MB
  u16* WT = (u16*)d_ws;              // 4 x 1M  (Wq_t, Wk_t, Wv_t, Wo_t)
  u16* QH = WT + 4 * 1048576;        // 4M  [b,h,s,d]
  u16* KH = QH + 4194304;            // 4M  [b,h,s,d]
  u16* VT = KH + 4194304;            // 4M  [b,h,d,s]
  u16* XB = VT + 4194304;            // 3 x 4M bf16 copies of q,k,v
  u16* AO = XB;                      // attn out aliases XB (dead by then)

  convx<<<dim3(4096, 3), 256, 0, stream>>>(query, key, value, XB);
  transw<<<dim3(16, 16, 4), 256, 0, stream>>>(Wq, Wk, Wv, Wo, WT);
  qkv_gemm<<<dim3(8, 32, 3), 256, 0, stream>>>(XB, WT, bq, bk, bv, QH, KH, VT);
  attn_kernel<<<dim3(16, 16, 2), 256, 0, stream>>>(QH, KH, VT, AO);
  oproj_gemm<<<dim3(8, 32), 256, 0, stream>>>(AO, WT + 3 * 1048576, bo, out);
}

// Round 2
// 240.065 us; speedup vs baseline: 1.1224x; 1.1224x over previous
//
#include <hip/hip_runtime.h>
#include <hip/hip_bf16.h>
#include <stdint.h>

typedef unsigned short u16;
typedef short bf16x8 __attribute__((ext_vector_type(8)));
typedef float f32x4 __attribute__((ext_vector_type(4)));

#define DEVI static __device__ __forceinline__

#if __has_builtin(__builtin_amdgcn_exp2f)
#define EXP2F(x) __builtin_amdgcn_exp2f(x)
#else
#define EXP2F(x) exp2f(x)
#endif

DEVI u16 f2bf(float f) {
  union { float f; uint32_t u; } v; v.f = f;
  uint32_t u = v.u;
  u += 0x7fffu + ((u >> 16) & 1u);   // round-to-nearest-even
  return (u16)(u >> 16);
}
DEVI uint32_t fbits(float f) { union { float f; uint32_t u; } v; v.f = f; return v.u; }
DEVI float asf(uint32_t u)   { union { uint32_t u; float f; } v; v.u = u; return v.f; }

DEVI void async16(const void* g, const void* l) {
  __builtin_amdgcn_global_load_lds(
      (const __attribute__((address_space(1))) void*)g,
      (__attribute__((address_space(3))) void*)l, 16, 0, 0);
}

DEVI f32x4 mfma16(bf16x8 a, bf16x8 b, f32x4 c) {
  return __builtin_amdgcn_mfma_f32_16x16x32_bf16(a, b, c, 0, 0, 0);
}

// ---------------------------------------------------------------- constants
// B=2, S=2048, H=1024, NH=16, D=64, M=B*S=4096
// log2(e)/sqrt(64): folded into Q at the qkv epilogue
#define CSC 0.18033688011112042f

// ------------------------------------------------- kernel 1: fp32 -> bf16 x
__global__ void convx(const float* __restrict__ q, const float* __restrict__ k,
                      const float* __restrict__ v, u16* __restrict__ out) {
  const int z = blockIdx.y;
  const float* src = (z == 0) ? q : (z == 1) ? k : v;
  const int i = (blockIdx.x * 256 + threadIdx.x) * 4;
  float4 f = *(const float4*)(src + i);
  ushort4 o;
  o.x = f2bf(f.x); o.y = f2bf(f.y); o.z = f2bf(f.z); o.w = f2bf(f.w);
  *(ushort4*)(out + (size_t)z * 4194304 + i) = o;
}

// ----------------------------------- kernel 2: W[k][n] -> Wt[n][k] in bf16
__global__ void transw(const float* __restrict__ Wq, const float* __restrict__ Wk,
                       const float* __restrict__ Wv, const float* __restrict__ Wo,
                       u16* __restrict__ WT) {
  __shared__ u16 tile[64 * 68];
  const int z = blockIdx.z;
  const float* W = (z == 0) ? Wq : (z == 1) ? Wk : (z == 2) ? Wv : Wo;
  u16* out = WT + (size_t)z * 1048576;
  const int R0 = blockIdx.y * 64, C0 = blockIdx.x * 64;
  const int t = threadIdx.x;
#pragma unroll
  for (int it = 0; it < 16; ++it) {
    int j = it * 256 + t;
    int r = j >> 6, c = j & 63;
    tile[r * 68 + c] = f2bf(W[(size_t)(R0 + r) * 1024 + C0 + c]);
  }
  __syncthreads();
#pragma unroll
  for (int it = 0; it < 16; ++it) {
    int j = it * 256 + t;
    int c = j >> 6, r = j & 63;
    out[(size_t)(C0 + c) * 1024 + R0 + r] = tile[r * 68 + c];
  }
}

// -------------------------------------------------- fused QKV projection GEMM
// z=0:Q (pre-scaled by CSC) z=1:K -> [b,h,s,d]; z=2:V -> [b,h,d,s]
__global__ __launch_bounds__(256, 3)
void qkv_gemm(const u16* __restrict__ XB, const u16* __restrict__ WT,
              const float* __restrict__ bq, const float* __restrict__ bk,
              const float* __restrict__ bv,
              u16* __restrict__ QH, u16* __restrict__ KH, u16* __restrict__ VT) {
  __shared__ u16 lA[128 * 32];
  __shared__ u16 lB[128 * 32];
  const int z = blockIdx.z;
  const u16* A  = XB + (size_t)z * 4194304;
  const u16* Bt = WT + (size_t)z * 1048576;
  const float* bias = (z == 0) ? bq : (z == 1) ? bk : bv;
  const int t = threadIdx.x, lane = t & 63, w = t >> 6;
  const int quad = lane >> 4, l16 = lane & 15;
  const int wm = (w & 1) * 64, wn = (w >> 1) * 64;
  const int n0 = blockIdx.x * 128, m0 = blockIdx.y * 128;

  f32x4 acc[4][4] = {};
  for (int kt = 0; kt < 32; ++kt) {
    const int k0 = kt * 32;
#pragma unroll
    for (int it = 0; it < 2; ++it) {
      int i = it * 256 + w * 64 + lane;
      int r = i >> 2, cc = i & 3, c = cc ^ (r & 3);
      async16(A + (size_t)(m0 + r) * 1024 + k0 + c * 8, &lA[(it * 256 + w * 64) * 8]);
      async16(Bt + (size_t)(n0 + r) * 1024 + k0 + c * 8, &lB[(it * 256 + w * 64) * 8]);
    }
    __syncthreads();
    bf16x8 af[4], bfr[4];
#pragma unroll
    for (int rt = 0; rt < 4; ++rt) {
      int row = wm + rt * 16 + l16;
      af[rt] = *(const bf16x8*)&lA[row * 32 + (quad ^ (row & 3)) * 8];
    }
#pragma unroll
    for (int ct = 0; ct < 4; ++ct) {
      int row = wn + ct * 16 + l16;
      bfr[ct] = *(const bf16x8*)&lB[row * 32 + (quad ^ (row & 3)) * 8];
    }
#pragma unroll
    for (int rt = 0; rt < 4; ++rt)
#pragma unroll
      for (int ct = 0; ct < 4; ++ct)
        acc[rt][ct] = mfma16(af[rt], bfr[ct], acc[rt][ct]);
    __syncthreads();
  }

  float bvv[4];
  int ncol[4];
#pragma unroll
  for (int ct = 0; ct < 4; ++ct) {
    ncol[ct] = n0 + wn + ct * 16 + l16;
    bvv[ct] = bias[ncol[ct]];
  }
  if (z < 2) {
    u16* out = (z == 0) ? QH : KH;
    const float scl = (z == 0) ? CSC : 1.0f;
#pragma unroll
    for (int rt = 0; rt < 4; ++rt)
#pragma unroll
      for (int r = 0; r < 4; ++r) {
        int m = m0 + wm + rt * 16 + quad * 4 + r;
        int bb = m >> 11, s = m & 2047;
#pragma unroll
        for (int ct = 0; ct < 4; ++ct) {
          int hh = ncol[ct] >> 6, d = ncol[ct] & 63;
          out[((size_t)((bb * 16 + hh) * 2048 + s)) * 64 + d] =
              f2bf((acc[rt][ct][r] + bvv[ct]) * scl);
        }
      }
  } else {
#pragma unroll
    for (int rt = 0; rt < 4; ++rt) {
      int mb = m0 + wm + rt * 16 + quad * 4;
      int bb = mb >> 11, sb = mb & 2047;
#pragma unroll
      for (int ct = 0; ct < 4; ++ct) {
        int hh = ncol[ct] >> 6, d = ncol[ct] & 63;
        ushort4 pk;
        pk.x = f2bf(acc[rt][ct][0] + bvv[ct]);
        pk.y = f2bf(acc[rt][ct][1] + bvv[ct]);
        pk.z = f2bf(acc[rt][ct][2] + bvv[ct]);
        pk.w = f2bf(acc[rt][ct][3] + bvv[ct]);
        *(ushort4*)&VT[((size_t)((bb * 16 + hh) * 64 + d)) * 2048 + sb] = pk;
      }
    }
  }
}

// -------------------------------------------------------- flash attention v2
// S^T formulation, no running max (exp2 of raw pre-scaled scores is safe),
// Sk-tile=64, double-buffered K/V staging, one barrier per tile.
// grid (qt=16, h=16, b=2); block 256 (4 waves); wave: 32 q rows.
__global__ __launch_bounds__(256, 2)
void attn2(const u16* __restrict__ QH, const u16* __restrict__ KH,
           const u16* __restrict__ VT, u16* __restrict__ AO) {
  __shared__ u16 lK[2][64 * 64];
  __shared__ u16 lV[2][64 * 64];
  __shared__ u16 lPT[4][32 * 64];
  const int qt0 = blockIdx.x, h = blockIdx.y, b = blockIdx.z;
  const int t = threadIdx.x, lane = t & 63, w = t >> 6;
  const int quad = lane >> 4, l16 = lane & 15;
  const u16* Qg = QH + ((size_t)((b * 16 + h) * 2048 + qt0 * 128)) * 64;
  const u16* Kg = KH + ((size_t)((b * 16 + h) * 2048)) * 64;
  const u16* Vg = VT + ((size_t)((b * 16 + h) * 64)) * 2048;

  // Q fragments straight from global (pre-scaled by CSC in qkv_gemm)
  bf16x8 qf[2][2];
#pragma unroll
  for (int qt = 0; qt < 2; ++qt)
#pragma unroll
    for (int ks = 0; ks < 2; ++ks)
      qf[qt][ks] = *(const bf16x8*)(Qg + (size_t)(w * 32 + qt * 16 + l16) * 64 +
                                    ks * 32 + quad * 8);

  // stage tile 0 (K: [64 sk][64 d], V: [64 d][64 sk]; XOR-chunk swizzled)
#pragma unroll
  for (int it = 0; it < 2; ++it) {
    int s = it * 256 + t;
    int r = s >> 3, cc = s & 7, c = cc ^ (r & 7);
    async16(Kg + (size_t)r * 64 + c * 8, &lK[0][s * 8]);
  }
#pragma unroll
  for (int it = 0; it < 2; ++it) {
    int s = it * 256 + t;
    int r = s >> 3, cc = s & 7, c = cc ^ (r & 7);
    async16(Vg + (size_t)r * 2048 + c * 8, &lV[0][s * 8]);
  }
  __syncthreads();

  f32x4 o[2][4] = {};
  float lsum[2] = {0.f, 0.f};
  const int swz = (l16 & 3) << 2;

  for (int kt = 0; kt < 32; ++kt) {
    const int cur = kt & 1, nxt = cur ^ 1;
    // prefetch next tile into the other buffer (drained at end-of-iter barrier)
    if (kt + 1 < 32) {
      const int kb = (kt + 1) * 64;
#pragma unroll
      for (int it = 0; it < 2; ++it) {
        int s = it * 256 + t;
        int r = s >> 3, cc = s & 7, c = cc ^ (r & 7);
        async16(Kg + (size_t)(kb + r) * 64 + c * 8, &lK[nxt][s * 8]);
      }
#pragma unroll
      for (int it = 0; it < 2; ++it) {
        int s = it * 256 + t;
        int r = s >> 3, cc = s & 7, c = cc ^ (r & 7);
        async16(Vg + (size_t)r * 2048 + kb + c * 8, &lV[nxt][s * 8]);
      }
    }

    // ---- QK^T -> S^T tiles: rows sk (quad*4+reg), cols q (l16)
    f32x4 sc[2][4];
#pragma unroll
    for (int st = 0; st < 4; ++st) {
      int row = st * 16 + l16;
      bf16x8 kf0 = *(const bf16x8*)&lK[cur][row * 64 + ((quad) ^ (row & 7)) * 8];
      bf16x8 kf1 = *(const bf16x8*)&lK[cur][row * 64 + ((4 + quad) ^ (row & 7)) * 8];
      f32x4 z = {};
      sc[0][st] = mfma16(kf0, qf[0][0], z);
      sc[0][st] = mfma16(kf1, qf[0][1], sc[0][st]);
      sc[1][st] = mfma16(kf0, qf[1][0], z);
      sc[1][st] = mfma16(kf1, qf[1][1], sc[1][st]);
    }

    // ---- p = exp2(s); truncate to bf16; l += truncated p; packed b64 writes
#pragma unroll
    for (int qt = 0; qt < 2; ++qt) {
      int row = qt * 16 + l16;
      float part = 0.f;
#pragma unroll
      for (int st = 0; st < 4; ++st) {
        uint32_t a0 = fbits(EXP2F(sc[qt][st][0])) & 0xffff0000u;
        uint32_t a1 = fbits(EXP2F(sc[qt][st][1])) & 0xffff0000u;
        uint32_t a2 = fbits(EXP2F(sc[qt][st][2])) & 0xffff0000u;
        uint32_t a3 = fbits(EXP2F(sc[qt][st][3])) & 0xffff0000u;
        part += (asf(a0) + asf(a1)) + (asf(a2) + asf(a3));
        uint2 pk;
        pk.x = a1 | (a0 >> 16);   // [sk+1 : sk+0]
        pk.y = a3 | (a2 >> 16);   // [sk+3 : sk+2]
        int g = (st * 4 + quad) ^ swz;          // 8B granule, swizzled
        *(uint2*)&lPT[w][row * 64 + g * 4] = pk;
      }
      lsum[qt] += part;
    }

    // ---- PV: O^T += V^T(64d x 64sk) * P(32q x 64sk)
#pragma unroll
    for (int ks2 = 0; ks2 < 2; ++ks2) {
      int g0 = (ks2 * 8 + quad * 2) ^ swz;
      bf16x8 pf0 = *(const bf16x8*)&lPT[w][(l16) * 64 + g0 * 4];
      bf16x8 pf1 = *(const bf16x8*)&lPT[w][(16 + l16) * 64 + g0 * 4];
#pragma unroll
      for (int dt = 0; dt < 4; ++dt) {
        int row = dt * 16 + l16;
        bf16x8 vf = *(const bf16x8*)&lV[cur][row * 64 + ((ks2 * 4 + quad) ^ (row & 7)) * 8];
        o[0][dt] = mfma16(vf, pf0, o[0][dt]);
        o[1][dt] = mfma16(vf, pf1, o[1][dt]);
      }
    }
    __syncthreads();
  }

  // ---- epilogue: O^T/l -> AO [b][s][h*64+d] bf16 (4 consecutive d per lane)
#pragma unroll
  for (int qt = 0; qt < 2; ++qt) {
    float l = lsum[qt];
    l += __shfl_xor(l, 16, 64);
    l += __shfl_xor(l, 32, 64);
    float inv = 1.0f / l;
    int qglob = qt0 * 128 + w * 32 + qt * 16 + l16;
    size_t base = ((size_t)(b * 2048 + qglob)) * 1024 + h * 64;
#pragma unroll
    for (int dt = 0; dt < 4; ++dt) {
      ushort4 pk;
      pk.x = f2bf(o[qt][dt][0] * inv);
      pk.y = f2bf(o[qt][dt][1] * inv);
      pk.z = f2bf(o[qt][dt][2] * inv);
      pk.w = f2bf(o[qt][dt][3] * inv);
      *(ushort4*)&AO[base + dt * 16 + quad * 4] = pk;
    }
  }
}

// ------------------------------------------------------- output projection
// 128m x 64n tiles -> 512 blocks (2/CU)
__global__ __launch_bounds__(256, 2)
void oproj_gemm(const u16* __restrict__ AO, const u16* __restrict__ Bt,
                const float* __restrict__ bias, float* __restrict__ out) {
  __shared__ u16 lA[128 * 32];
  __shared__ u16 lB[64 * 32];
  const int t = threadIdx.x, lane = t & 63, w = t >> 6;
  const int quad = lane >> 4, l16 = lane & 15;
  const int wm = (w & 1) * 64, wn = (w >> 1) * 32;
  const int n0 = blockIdx.x * 64, m0 = blockIdx.y * 128;

  f32x4 acc[4][2] = {};
  for (int kt = 0; kt < 32; ++kt) {
    const int k0 = kt * 32;
#pragma unroll
    for (int it = 0; it < 2; ++it) {
      int i = it * 256 + t;
      int r = i >> 2, cc = i & 3, c = cc ^ (r & 3);
      async16(AO + (size_t)(m0 + r) * 1024 + k0 + c * 8, &lA[i * 8]);
    }
    {
      int i = t;
      int r = i >> 2, cc = i & 3, c = cc ^ (r & 3);
      async16(Bt + (size_t)(n0 + r) * 1024 + k0 + c * 8, &lB[i * 8]);
    }
    __syncthreads();
    bf16x8 af[4], bfr[2];
#pragma unroll
    for (int rt = 0; rt < 4; ++rt) {
      int row = wm + rt * 16 + l16;
      af[rt] = *(const bf16x8*)&lA[row * 32 + (quad ^ (row & 3)) * 8];
    }
#pragma unroll
    for (int ct = 0; ct < 2; ++ct) {
      int row = wn + ct * 16 + l16;
      bfr[ct] = *(const bf16x8*)&lB[row * 32 + (quad ^ (row & 3)) * 8];
    }
#pragma unroll
    for (int rt = 0; rt < 4; ++rt)
#pragma unroll
      for (int ct = 0; ct < 2; ++ct)
        acc[rt][ct] = mfma16(af[rt], bfr[ct], acc[rt][ct]);
    __syncthreads();
  }

#pragma unroll
  for (int ct = 0; ct < 2; ++ct) {
    int ncol = n0 + wn + ct * 16 + l16;
    float bvv = bias[ncol];
#pragma unroll
    for (int rt = 0; rt < 4; ++rt)
#pragma unroll
      for (int r = 0; r < 4; ++r) {
        int m = m0 + wm + rt * 16 + quad * 4 + r;
        out[(size_t)m * 1024 + ncol] = acc[rt][ct][r] + bvv;
      }
  }
}

// ------------------------------------------------------------------ launch
extern "C" void kernel_launch(void* const* d_in, const int* in_sizes, int n_in,
                              void* d_out, int out_size, void* d_ws, size_t ws_size,
                              hipStream_t stream) {
  const float* query = (const float*)d_in[0];
  const float* key   = (const float*)d_in[1];
  const float* value = (const float*)d_in[2];
  const float* Wq = (const float*)d_in[3];
  const float* bq = (const float*)d_in[4];
  const float* Wk = (const float*)d_in[5];
  const float* bk = (const float*)d_in[6];
  const float* Wv = (const float*)d_in[7];
  const float* bv = (const float*)d_in[8];
  const float* Wo = (const float*)d_in[9];
  const float* bo = (const float*)d_in[10];
  float* out = (float*)d_out;

  // workspace layout (u16 elements): total 28M u16 = 56 MB
  u16* WT = (u16*)d_ws;              // 4 x 1M  (Wq_t, Wk_t, Wv_t, Wo_t)
  u16* QH = WT + 4 * 1048576;        // 4M  [b,h,s,d]  (Q pre-scaled by CSC)
  u16* KH = QH + 4194304;            // 4M  [b,h,s,d]
  u16* VT = KH + 4194304;            // 4M  [b,h,d,s]
  u16* XB = VT + 4194304;            // 3 x 4M bf16 copies of q,k,v
  u16* AO = XB;                      // attn out aliases XB (dead by then)

  convx<<<dim3(4096, 3), 256, 0, stream>>>(query, key, value, XB);
  transw<<<dim3(16, 16, 4), 256, 0, stream>>>(Wq, Wk, Wv, Wo, WT);
  qkv_gemm<<<dim3(8, 32, 3), 256, 0, stream>>>(XB, WT, bq, bk, bv, QH, KH, VT);
  attn2<<<dim3(16, 16, 2), 256, 0, stream>>>(QH, KH, VT, AO);
  oproj_gemm<<<dim3(16, 32), 256, 0, stream>>>(AO, WT + 3 * 1048576, bo, out);
}

// Round 3
// 222.691 us; speedup vs baseline: 1.2100x; 1.0780x over previous
//
#include <hip/hip_runtime.h>
#include <hip/hip_bf16.h>
#include <stdint.h>

typedef unsigned short u16;
typedef short bf16x8 __attribute__((ext_vector_type(8)));
typedef float f32x4 __attribute__((ext_vector_type(4)));

#define DEVI static __device__ __forceinline__

#if __has_builtin(__builtin_amdgcn_exp2f)
#define EXP2F(x) __builtin_amdgcn_exp2f(x)
#else
#define EXP2F(x) exp2f(x)
#endif

DEVI u16 f2bf(float f) {
  union { float f; uint32_t u; } v; v.f = f;
  uint32_t u = v.u;
  u += 0x7fffu + ((u >> 16) & 1u);   // round-to-nearest-even
  return (u16)(u >> 16);
}
DEVI uint32_t pk2bf(float lo, float hi) {
  __hip_bfloat162 h = __float22bfloat162_rn(float2{lo, hi});
  union { __hip_bfloat162 h; uint32_t u; } v; v.h = h; return v.u;
}

DEVI void async16(const void* g, const void* l) {
  __builtin_amdgcn_global_load_lds(
      (const __attribute__((address_space(1))) void*)g,
      (__attribute__((address_space(3))) void*)l, 16, 0, 0);
}

DEVI f32x4 mfma16(bf16x8 a, bf16x8 b, f32x4 c) {
  return __builtin_amdgcn_mfma_f32_16x16x32_bf16(a, b, c, 0, 0, 0);
}

// ---------------------------------------------------------------- constants
// B=2, S=2048, H=1024, NH=16, D=64, M=B*S=4096
// log2(e)/sqrt(64): folded into Q at the qkv epilogue
#define CSC 0.18033688011112042f

// ------------------------------------------------- kernel 1: fp32 -> bf16 x
__global__ void convx(const float* __restrict__ q, const float* __restrict__ k,
                      const float* __restrict__ v, u16* __restrict__ out) {
  const int z = blockIdx.y;
  const float* src = (z == 0) ? q : (z == 1) ? k : v;
  const int i = (blockIdx.x * 256 + threadIdx.x) * 4;
  float4 f = *(const float4*)(src + i);
  ushort4 o;
  o.x = f2bf(f.x); o.y = f2bf(f.y); o.z = f2bf(f.z); o.w = f2bf(f.w);
  *(ushort4*)(out + (size_t)z * 4194304 + i) = o;
}

// ----------------------------------- kernel 2: W[k][n] -> Wt[n][k] in bf16
__global__ void transw(const float* __restrict__ Wq, const float* __restrict__ Wk,
                       const float* __restrict__ Wv, const float* __restrict__ Wo,
                       u16* __restrict__ WT) {
  __shared__ u16 tile[64 * 68];
  const int z = blockIdx.z;
  const float* W = (z == 0) ? Wq : (z == 1) ? Wk : (z == 2) ? Wv : Wo;
  u16* out = WT + (size_t)z * 1048576;
  const int R0 = blockIdx.y * 64, C0 = blockIdx.x * 64;
  const int t = threadIdx.x;
#pragma unroll
  for (int it = 0; it < 16; ++it) {
    int j = it * 256 + t;
    int r = j >> 6, c = j & 63;
    tile[r * 68 + c] = f2bf(W[(size_t)(R0 + r) * 1024 + C0 + c]);
  }
  __syncthreads();
#pragma unroll
  for (int it = 0; it < 16; ++it) {
    int j = it * 256 + t;
    int c = j >> 6, r = j & 63;
    out[(size_t)(C0 + c) * 1024 + R0 + r] = tile[r * 68 + c];
  }
}

// -------------------------------------------------- fused QKV projection GEMM
// BK=64, 16 k-iters. z=0:Q (pre-scaled by CSC) z=1:K -> [b,h,s,d]; z=2:V -> [b,h,d,s]
__global__ __launch_bounds__(256, 3)
void qkv_gemm(const u16* __restrict__ XB, const u16* __restrict__ WT,
              const float* __restrict__ bq, const float* __restrict__ bk,
              const float* __restrict__ bv,
              u16* __restrict__ QH, u16* __restrict__ KH, u16* __restrict__ VT) {
  __shared__ u16 lA[128 * 64];
  __shared__ u16 lB[128 * 64];
  const int z = blockIdx.z;
  const u16* A  = XB + (size_t)z * 4194304;
  const u16* Bt = WT + (size_t)z * 1048576;
  const float* bias = (z == 0) ? bq : (z == 1) ? bk : bv;
  const int t = threadIdx.x, lane = t & 63, w = t >> 6;
  const int quad = lane >> 4, l16 = lane & 15;
  const int wm = (w & 1) * 64, wn = (w >> 1) * 64;
  const int n0 = blockIdx.x * 128, m0 = blockIdx.y * 128;

  f32x4 acc[4][4] = {};
  for (int kt = 0; kt < 16; ++kt) {
    const int k0 = kt * 64;
#pragma unroll
    for (int it = 0; it < 4; ++it) {
      int i = it * 256 + t;
      int r = i >> 3, cc = i & 7, c = cc ^ (r & 7);
      async16(A + (size_t)(m0 + r) * 1024 + k0 + c * 8, &lA[i * 8]);
      async16(Bt + (size_t)(n0 + r) * 1024 + k0 + c * 8, &lB[i * 8]);
    }
    __syncthreads();
#pragma unroll
    for (int ks = 0; ks < 2; ++ks) {
      bf16x8 af[4], bfr[4];
#pragma unroll
      for (int rt = 0; rt < 4; ++rt) {
        int row = wm + rt * 16 + l16;
        af[rt] = *(const bf16x8*)&lA[row * 64 + ((ks * 4 + quad) ^ (row & 7)) * 8];
      }
#pragma unroll
      for (int ct = 0; ct < 4; ++ct) {
        int row = wn + ct * 16 + l16;
        bfr[ct] = *(const bf16x8*)&lB[row * 64 + ((ks * 4 + quad) ^ (row & 7)) * 8];
      }
#pragma unroll
      for (int rt = 0; rt < 4; ++rt)
#pragma unroll
        for (int ct = 0; ct < 4; ++ct)
          acc[rt][ct] = mfma16(af[rt], bfr[ct], acc[rt][ct]);
    }
    __syncthreads();
  }

  float bvv[4];
  int ncol[4];
#pragma unroll
  for (int ct = 0; ct < 4; ++ct) {
    ncol[ct] = n0 + wn + ct * 16 + l16;
    bvv[ct] = bias[ncol[ct]];
  }
  if (z < 2) {
    u16* out = (z == 0) ? QH : KH;
    const float scl = (z == 0) ? CSC : 1.0f;
#pragma unroll
    for (int rt = 0; rt < 4; ++rt)
#pragma unroll
      for (int r = 0; r < 4; ++r) {
        int m = m0 + wm + rt * 16 + quad * 4 + r;
        int bb = m >> 11, s = m & 2047;
#pragma unroll
        for (int ct = 0; ct < 4; ++ct) {
          int hh = ncol[ct] >> 6, d = ncol[ct] & 63;
          out[((size_t)((bb * 16 + hh) * 2048 + s)) * 64 + d] =
              f2bf((acc[rt][ct][r] + bvv[ct]) * scl);
        }
      }
  } else {
#pragma unroll
    for (int rt = 0; rt < 4; ++rt) {
      int mb = m0 + wm + rt * 16 + quad * 4;
      int bb = mb >> 11, sb = mb & 2047;
#pragma unroll
      for (int ct = 0; ct < 4; ++ct) {
        int hh = ncol[ct] >> 6, d = ncol[ct] & 63;
        ushort4 pk;
        pk.x = f2bf(acc[rt][ct][0] + bvv[ct]);
        pk.y = f2bf(acc[rt][ct][1] + bvv[ct]);
        pk.z = f2bf(acc[rt][ct][2] + bvv[ct]);
        pk.w = f2bf(acc[rt][ct][3] + bvv[ct]);
        *(ushort4*)&VT[((size_t)((bb * 16 + hh) * 64 + d)) * 2048 + sb] = pk;
      }
    }
  }
}

// -------------------------------------------------------- flash attention v3
// 512 threads (8 waves x 16 q rows). S^T formulation, no running max,
// Sk-tile=64, double-buffered K/V, one barrier/tile, per-wave padded lPT.
// grid (qt=16, h=16, b=2).
__global__ __launch_bounds__(512, 4)
void attn3(const u16* __restrict__ QH, const u16* __restrict__ KH,
           const u16* __restrict__ VT, u16* __restrict__ AO) {
  __shared__ u16 lK[2][64 * 64];
  __shared__ u16 lV[2][64 * 64];
  __shared__ u16 lPT[8][16 * 72];   // stride 72: b64 writes 4/bank, b128 reads 8/bank
  const int qt0 = blockIdx.x, h = blockIdx.y, b = blockIdx.z;
  const int t = threadIdx.x, lane = t & 63, w = t >> 6;
  const int quad = lane >> 4, l16 = lane & 15;
  const u16* Qg = QH + ((size_t)((b * 16 + h) * 2048 + qt0 * 128)) * 64;
  const u16* Kg = KH + ((size_t)((b * 16 + h) * 2048)) * 64;
  const u16* Vg = VT + ((size_t)((b * 16 + h) * 64)) * 2048;

  // Q fragments straight from global (pre-scaled by CSC in qkv_gemm)
  bf16x8 qf[2];
#pragma unroll
  for (int ks = 0; ks < 2; ++ks)
    qf[ks] = *(const bf16x8*)(Qg + (size_t)(w * 16 + l16) * 64 + ks * 32 + quad * 8);

  // stage tile 0: K [64 sk][64 d], V [64 d][64 sk]; one async16 per thread each
  {
    int r = t >> 3, cc = t & 7, c = cc ^ (r & 7);
    async16(Kg + (size_t)r * 64 + c * 8, &lK[0][t * 8]);
    async16(Vg + (size_t)r * 2048 + c * 8, &lV[0][t * 8]);
  }
  __syncthreads();

  f32x4 o[4] = {};
  float lsum = 0.f;
  u16* myP = &lPT[w][0];

  for (int kt = 0; kt < 32; ++kt) {
    const int cur = kt & 1, nxt = cur ^ 1;
    if (kt + 1 < 32) {
      const int kb = (kt + 1) * 64;
      int r = t >> 3, cc = t & 7, c = cc ^ (r & 7);
      async16(Kg + (size_t)(kb + r) * 64 + c * 8, &lK[nxt][t * 8]);
      async16(Vg + (size_t)r * 2048 + kb + c * 8, &lV[nxt][t * 8]);
    }

    // ---- QK^T -> S^T: rows sk (st*16+quad*4+r), cols q (l16)
    f32x4 sc[4];
#pragma unroll
    for (int st = 0; st < 4; ++st) {
      int row = st * 16 + l16;
      bf16x8 kf0 = *(const bf16x8*)&lK[cur][row * 64 + ((quad) ^ (row & 7)) * 8];
      bf16x8 kf1 = *(const bf16x8*)&lK[cur][row * 64 + ((4 + quad) ^ (row & 7)) * 8];
      f32x4 z = {};
      sc[st] = mfma16(kf0, qf[0], z);
      sc[st] = mfma16(kf1, qf[1], sc[st]);
    }

    // ---- p = exp2(s); pack RNE bf16 pairs; l += fp32 p
#pragma unroll
    for (int st = 0; st < 4; ++st) {
      float p0 = EXP2F(sc[st][0]);
      float p1 = EXP2F(sc[st][1]);
      float p2 = EXP2F(sc[st][2]);
      float p3 = EXP2F(sc[st][3]);
      lsum += (p0 + p1) + (p2 + p3);
      uint2 pk;
      pk.x = pk2bf(p0, p1);
      pk.y = pk2bf(p2, p3);
      // row q=l16 (stride 72), sk offset st*16+quad*4
      *(uint2*)&myP[l16 * 72 + st * 16 + quad * 4] = pk;
    }

    // ---- PV: O^T += V^T(64d x 64sk) * P(16q x 64sk)
#pragma unroll
    for (int ks2 = 0; ks2 < 2; ++ks2) {
      bf16x8 pf = *(const bf16x8*)&myP[l16 * 72 + ks2 * 32 + quad * 8];
#pragma unroll
      for (int dt = 0; dt < 4; ++dt) {
        int row = dt * 16 + l16;
        bf16x8 vf = *(const bf16x8*)&lV[cur][row * 64 + ((ks2 * 4 + quad) ^ (row & 7)) * 8];
        o[dt] = mfma16(vf, pf, o[dt]);
      }
    }
    __syncthreads();
  }

  // ---- epilogue: O^T/l -> AO [b][s][h*64+d] bf16 (4 consecutive d per lane)
  float l = lsum;
  l += __shfl_xor(l, 16, 64);
  l += __shfl_xor(l, 32, 64);
  float inv = 1.0f / l;
  int qglob = qt0 * 128 + w * 16 + l16;
  size_t base = ((size_t)(b * 2048 + qglob)) * 1024 + h * 64;
#pragma unroll
  for (int dt = 0; dt < 4; ++dt) {
    ushort4 pk;
    pk.x = f2bf(o[dt][0] * inv);
    pk.y = f2bf(o[dt][1] * inv);
    pk.z = f2bf(o[dt][2] * inv);
    pk.w = f2bf(o[dt][3] * inv);
    *(ushort4*)&AO[base + dt * 16 + quad * 4] = pk;
  }
}

// ------------------------------------------------------- output projection
// 128m x 64n tiles, BK=64 -> 512 blocks
__global__ __launch_bounds__(256, 2)
void oproj_gemm(const u16* __restrict__ AO, const u16* __restrict__ Bt,
                const float* __restrict__ bias, float* __restrict__ out) {
  __shared__ u16 lA[128 * 64];
  __shared__ u16 lB[64 * 64];
  const int t = threadIdx.x, lane = t & 63, w = t >> 6;
  const int quad = lane >> 4, l16 = lane & 15;
  const int wm = (w & 1) * 64, wn = (w >> 1) * 32;
  const int n0 = blockIdx.x * 64, m0 = blockIdx.y * 128;

  f32x4 acc[4][2] = {};
  for (int kt = 0; kt < 16; ++kt) {
    const int k0 = kt * 64;
#pragma unroll
    for (int it = 0; it < 4; ++it) {
      int i = it * 256 + t;
      int r = i >> 3, cc = i & 7, c = cc ^ (r & 7);
      async16(AO + (size_t)(m0 + r) * 1024 + k0 + c * 8, &lA[i * 8]);
    }
#pragma unroll
    for (int it = 0; it < 2; ++it) {
      int i = it * 256 + t;
      int r = i >> 3, cc = i & 7, c = cc ^ (r & 7);
      async16(Bt + (size_t)(n0 + r) * 1024 + k0 + c * 8, &lB[i * 8]);
    }
    __syncthreads();
#pragma unroll
    for (int ks = 0; ks < 2; ++ks) {
      bf16x8 af[4], bfr[2];
#pragma unroll
      for (int rt = 0; rt < 4; ++rt) {
        int row = wm + rt * 16 + l16;
        af[rt] = *(const bf16x8*)&lA[row * 64 + ((ks * 4 + quad) ^ (row & 7)) * 8];
      }
#pragma unroll
      for (int ct = 0; ct < 2; ++ct) {
        int row = wn + ct * 16 + l16;
        bfr[ct] = *(const bf16x8*)&lB[row * 64 + ((ks * 4 + quad) ^ (row & 7)) * 8];
      }
#pragma unroll
      for (int rt = 0; rt < 4; ++rt)
#pragma unroll
        for (int ct = 0; ct < 2; ++ct)
          acc[rt][ct] = mfma16(af[rt], bfr[ct], acc[rt][ct]);
    }
    __syncthreads();
  }

#pragma unroll
  for (int ct = 0; ct < 2; ++ct) {
    int ncol = n0 + wn + ct * 16 + l16;
    float bvv = bias[ncol];
#pragma unroll
    for (int rt = 0; rt < 4; ++rt)
#pragma unroll
      for (int r = 0; r < 4; ++r) {
        int m = m0 + wm + rt * 16 + quad * 4 + r;
        out[(size_t)m * 1024 + ncol] = acc[rt][ct][r] + bvv;
      }
  }
}

// ------------------------------------------------------------------ launch
extern "C" void kernel_launch(void* const* d_in, const int* in_sizes, int n_in,
                              void* d_out, int out_size, void* d_ws, size_t ws_size,
                              hipStream_t stream) {
  const float* query = (const float*)d_in[0];
  const float* key   = (const float*)d_in[1];
  const float* value = (const float*)d_in[2];
  const float* Wq = (const float*)d_in[3];
  const float* bq = (const float*)d_in[4];
  const float* Wk = (const float*)d_in[5];
  const float* bk = (const float*)d_in[6];
  const float* Wv = (const float*)d_in[7];
  const float* bv = (const float*)d_in[8];
  const float* Wo = (const float*)d_in[9];
  const float* bo = (const float*)d_in[10];
  float* out = (float*)d_out;

  // workspace layout (u16 elements): total 28M u16 = 56 MB
  u16* WT = (u16*)d_ws;              // 4 x 1M  (Wq_t, Wk_t, Wv_t, Wo_t)
  u16* QH = WT + 4 * 1048576;        // 4M  [b,h,s,d]  (Q pre-scaled by CSC)
  u16* KH = QH + 4194304;            // 4M  [b,h,s,d]
  u16* VT = KH + 4194304;            // 4M  [b,h,d,s]
  u16* XB = VT + 4194304;            // 3 x 4M bf16 copies of q,k,v
  u16* AO = XB;                      // attn out aliases XB (dead by then)

  convx<<<dim3(4096, 3), 256, 0, stream>>>(query, key, value, XB);
  transw<<<dim3(16, 16, 4), 256, 0, stream>>>(Wq, Wk, Wv, Wo, WT);
  qkv_gemm<<<dim3(8, 32, 3), 256, 0, stream>>>(XB, WT, bq, bk, bv, QH, KH, VT);
  attn3<<<dim3(16, 16, 2), 512, 0, stream>>>(QH, KH, VT, AO);
  oproj_gemm<<<dim3(16, 32), 256, 0, stream>>>(AO, WT + 3 * 1048576, bo, out);
}